// Round 3
// baseline (1110.991 us; speedup 1.0000x reference)
//
#include <hip/hip_runtime.h>
#include <hip/hip_bf16.h>

typedef unsigned long long u64;

#define S_STEPS 101
#define BATCH   2048
#define DIN     120
#define HID     200
#define DOUT    12

// ---------------------------------------------------------------------------
// Kernel 1: layer 1 — dense cur1 = xt@W1 + b1, LIF recurrence, emit spike masks
// grid 512 x 256; block handles 4 batches; thread tid = neuron h (h<200 active)
// W1 column lives in 120 registers (static indexing only); xt staged via LDS.
// ---------------------------------------------------------------------------
__global__ __launch_bounds__(256) void k_layer1(
    const float* __restrict__ x, const float* __restrict__ W1,
    const float* __restrict__ b1, u64* __restrict__ s1m)
{
  __shared__ float xt_s[4 * DIN];          // 1.9 KB
  const int tid  = threadIdx.x;
  const int b0   = blockIdx.x * 4;
  const int lane = tid & 63;
  const bool act = tid < HID;

  // W1[:, h] -> registers (guarded: W1 has 120*200 elements)
  float w1r[DIN];
#pragma unroll
  for (int k = 0; k < DIN; ++k)
    w1r[k] = act ? W1[k * HID + tid] : 0.0f;
  const float bias = act ? b1[tid] : 0.0f;

  // staging source addresses for elements e = tid and e = tid+256 (e < 480)
  long base0, base1 = -1;
  {
    int e = tid;
    int i = e / DIN, r = e % DIN, c = r / 40, m = r % 40;
    base0 = ((long)(b0 + i) * 3 + c) * (S_STEPS * 40) + m;
    e = tid + 256;
    if (e < 4 * DIN) {
      i = e / DIN; r = e % DIN; c = r / 40; m = r % 40;
      base1 = ((long)(b0 + i) * 3 + c) * (S_STEPS * 40) + m;
    }
  }

  float v0 = 0.f, v1 = 0.f, v2 = 0.f, v3 = 0.f;

#pragma unroll 1
  for (int t = 0; t < S_STEPS; ++t) {
    // stage xt tile [4][120]
    xt_s[tid] = x[base0 + 40 * t];
    if (base1 >= 0) xt_s[tid + 256] = x[base1 + 40 * t];
    __syncthreads();

    float a0 = bias, a1 = bias, a2 = bias, a3 = bias;
    const float4* xs4 = (const float4*)xt_s;
#pragma unroll
    for (int kq = 0; kq < DIN / 4; ++kq) {
      float4 xa = xs4[0 * (DIN / 4) + kq];
      float4 xb = xs4[1 * (DIN / 4) + kq];
      float4 xc = xs4[2 * (DIN / 4) + kq];
      float4 xd = xs4[3 * (DIN / 4) + kq];
      float w;
      w = w1r[4 * kq + 0]; a0 += w * xa.x; a1 += w * xb.x; a2 += w * xc.x; a3 += w * xd.x;
      w = w1r[4 * kq + 1]; a0 += w * xa.y; a1 += w * xb.y; a2 += w * xc.y; a3 += w * xd.y;
      w = w1r[4 * kq + 2]; a0 += w * xa.z; a1 += w * xb.z; a2 += w * xc.z; a3 += w * xd.z;
      w = w1r[4 * kq + 3]; a0 += w * xa.w; a1 += w * xb.w; a2 += w * xc.w; a3 += w * xd.w;
    }
    __syncthreads();

    u64* mp = s1m + ((size_t)t * BATCH + b0) * 4 + (tid >> 6);
    // LIF update + ballot per batch (exact reference op order)
    {
      v0 = v0 + 0.5f * (a0 - v0);
      bool sp = act && (v0 >= 1.0f); if (sp) v0 = 0.0f;
      u64 bal = __ballot(sp); if (lane == 0) mp[0] = bal;
    }
    {
      v1 = v1 + 0.5f * (a1 - v1);
      bool sp = act && (v1 >= 1.0f); if (sp) v1 = 0.0f;
      u64 bal = __ballot(sp); if (lane == 0) mp[4] = bal;
    }
    {
      v2 = v2 + 0.5f * (a2 - v2);
      bool sp = act && (v2 >= 1.0f); if (sp) v2 = 0.0f;
      u64 bal = __ballot(sp); if (lane == 0) mp[8] = bal;
    }
    {
      v3 = v3 + 0.5f * (a3 - v3);
      bool sp = act && (v3 >= 1.0f); if (sp) v3 = 0.0f;
      u64 bal = __ballot(sp); if (lane == 0) mp[12] = bal;
    }
  }
}

// ---------------------------------------------------------------------------
// Kernels 2/3: recurrent layer driven by spike masks.
// cur[b][h] = bias[h] + sum_{k in mask(b)} W[k][h], W fp32 in dynamic LDS.
// grid 256 x 256; block handles 8 batches; masks are wave-uniform (scalar).
// CNT: also accumulate per-(b,h) spike counts (layer 3); mout may be null.
// ---------------------------------------------------------------------------
template <bool CNT>
__global__ __launch_bounds__(256) void k_rec(
    const float* __restrict__ W, const float* __restrict__ bias,
    const u64* __restrict__ min_, u64* __restrict__ mout,
    float* __restrict__ cnt)
{
  extern __shared__ float Ws[];            // 160256 B allocated (40064 floats)
  const int tid  = threadIdx.x;
  const int b0   = blockIdx.x * 8;
  const int lane = tid & 63;
  const bool act = tid < HID;

  // stage W (200x200) into LDS, float4-coalesced
  {
    const float4* Wg = (const float4*)W;
    float4* Wl = (float4*)Ws;
#pragma unroll
    for (int r = 0; r < 40; ++r) {
      int idx = r * 256 + tid;
      if (idx < (HID * HID) / 4) Wl[idx] = Wg[idx];
    }
  }
  const float bv = act ? bias[tid] : 0.0f;
  float v[8]  = {0, 0, 0, 0, 0, 0, 0, 0};
  float c8[8] = {0, 0, 0, 0, 0, 0, 0, 0};
  __syncthreads();

#pragma unroll 1
  for (int t = 0; t < S_STEPS; ++t) {
    const u64* mp = min_ + ((size_t)t * BATCH + b0) * 4;
    u64 mm[8][4];
#pragma unroll
    for (int i = 0; i < 8; ++i)
#pragma unroll
      for (int w = 0; w < 4; ++w) mm[i][w] = mp[i * 4 + w];

    float acc[8];
#pragma unroll
    for (int i = 0; i < 8; ++i) acc[i] = bv;

#pragma unroll
    for (int w = 0; w < 4; ++w) {
      while ((mm[0][w] | mm[1][w] | mm[2][w] | mm[3][w] |
              mm[4][w] | mm[5][w] | mm[6][w] | mm[7][w]) != 0ull) {
#pragma unroll
        for (int i = 0; i < 8; ++i) {
          u64 m = mm[i][w];
          if (m) {                               // wave-uniform branch
            int k = __builtin_ctzll(m);
            mm[i][w] = m & (m - 1);
            acc[i] += Ws[(w * 64 + k) * HID + tid];
          }
        }
      }
    }

#pragma unroll
    for (int i = 0; i < 8; ++i) {
      v[i] = v[i] + 0.5f * (acc[i] - v[i]);
      bool sp = act && (v[i] >= 1.0f);
      if (sp) v[i] = 0.0f;
      if (CNT) c8[i] += sp ? 1.0f : 0.0f;
      u64 bal = __ballot(sp);
      if (mout && lane == 0)
        mout[((size_t)t * BATCH + b0 + i) * 4 + (tid >> 6)] = bal;
    }
  }

  if (CNT && act) {
#pragma unroll
    for (int i = 0; i < 8; ++i)
      cnt[(size_t)(b0 + i) * HID + tid] = c8[i];
  }
}

// ---------------------------------------------------------------------------
// Kernel 4: out = (cnt/101) @ Wr + br, then log_softmax over 12 classes.
// grid 32 x 256; block handles 64 batches; everything via static LDS (<64KB).
// ---------------------------------------------------------------------------
__global__ __launch_bounds__(256) void k_readout(
    const float* __restrict__ cnt, const float* __restrict__ Wr,
    const float* __restrict__ br, float* __restrict__ out)
{
  __shared__ float cs[64 * HID];     // 51200 B
  __shared__ float Wrs[HID * DOUT];  // 9600 B
  __shared__ float brs[DOUT];
  __shared__ float os[64 * DOUT];    // 3072 B
  const int tid = threadIdx.x;
  const int b0  = blockIdx.x * 64;

#pragma unroll
  for (int r = 0; r < 50; ++r)
    cs[r * 256 + tid] = cnt[(size_t)b0 * HID + r * 256 + tid];
  for (int idx = tid; idx < HID * DOUT; idx += 256) Wrs[idx] = Wr[idx];
  if (tid < DOUT) brs[tid] = br[tid];
  __syncthreads();

#pragma unroll
  for (int rep = 0; rep < 3; ++rep) {
    int idx = rep * 256 + tid;       // < 768 = 64*12
    int bl = idx / DOUT, j = idx % DOUT;
    float a = 0.0f;
    for (int k = 0; k < HID; ++k)
      a += cs[bl * HID + k] * Wrs[k * DOUT + j];
    os[idx] = a * (1.0f / 101.0f) + brs[j];
  }
  __syncthreads();

  if (tid < 64) {
    float o[DOUT];
#pragma unroll
    for (int j = 0; j < DOUT; ++j) o[j] = os[tid * DOUT + j];
    float mx = o[0];
#pragma unroll
    for (int j = 1; j < DOUT; ++j) mx = fmaxf(mx, o[j]);
    float s = 0.0f;
#pragma unroll
    for (int j = 0; j < DOUT; ++j) s += expf(o[j] - mx);
    float ls = logf(s);
    float* op = out + (size_t)(b0 + tid) * DOUT;
#pragma unroll
    for (int j = 0; j < DOUT; ++j) op[j] = o[j] - mx - ls;
  }
}

// ---------------------------------------------------------------------------
extern "C" void kernel_launch(void* const* d_in, const int* in_sizes, int n_in,
                              void* d_out, int out_size, void* d_ws, size_t ws_size,
                              hipStream_t stream)
{
  const float* x  = (const float*)d_in[0];
  const float* W1 = (const float*)d_in[1];
  const float* b1 = (const float*)d_in[2];
  const float* W2 = (const float*)d_in[3];
  const float* b2 = (const float*)d_in[4];
  const float* W3 = (const float*)d_in[5];
  const float* b3 = (const float*)d_in[6];
  const float* Wr = (const float*)d_in[7];
  const float* br = (const float*)d_in[8];
  float* out = (float*)d_out;

  // workspace layout: 2 spike-mask arrays [101][2048][4]u64 + count [2048][200]f32
  char* w = (char*)d_ws;
  const size_t mbytes = (size_t)S_STEPS * BATCH * 4 * sizeof(u64); // 6,619,136 B
  u64* s1m   = (u64*)(w);
  u64* s2m   = (u64*)(w + mbytes);
  float* cnt = (float*)(w + 2 * mbytes);   // total ~14.9 MB

  // allow 160,256 B dynamic LDS for k_rec (gfx950: 160 KiB per workgroup)
  {
    void (*f2)(const float*, const float*, const u64*, u64*, float*) = k_rec<false>;
    void (*f3)(const float*, const float*, const u64*, u64*, float*) = k_rec<true>;
    hipFuncSetAttribute((const void*)f2, hipFuncAttributeMaxDynamicSharedMemorySize, 160256);
    hipFuncSetAttribute((const void*)f3, hipFuncAttributeMaxDynamicSharedMemorySize, 160256);
  }

  k_layer1<<<BATCH / 4, 256, 0, stream>>>(x, W1, b1, s1m);
  k_rec<false><<<BATCH / 8, 256, 160256, stream>>>(W2, b2, s1m, s2m, nullptr);
  k_rec<true ><<<BATCH / 8, 256, 160256, stream>>>(W3, b3, s2m, nullptr, cnt);
  k_readout<<<32, 256, 0, stream>>>(cnt, Wr, br, out);
}

// Round 4
// 379.540 us; speedup vs baseline: 2.9272x; 2.9272x over previous
//
#include <hip/hip_runtime.h>
#include <hip/hip_bf16.h>

typedef unsigned long long u64;
typedef __attribute__((ext_vector_type(8))) short short8;
typedef __attribute__((ext_vector_type(4))) float f32x4;

#define S_STEPS 101
#define BATCH   2048
#define DIN     120
#define HID     200
#define DOUT    12

// round-to-nearest-even f32 -> bf16 (as ushort)
__device__ __forceinline__ ushort f2bf(float f) {
  union { float f; unsigned u; } c; c.f = f;
  unsigned r = (c.u + 0x7FFFu + ((c.u >> 16) & 1u)) >> 16;
  return (ushort)r;
}
__device__ __forceinline__ float bf2f(ushort s) {
  union { unsigned u; float f; } c; c.u = ((unsigned)s) << 16;
  return c.f;
}

// ---------------------------------------------------------------------------
// k_l1: fused layer-1. Block = 16 batches, ALL 101 timesteps.
// grid 128 x 256 (4 waves). Wave w owns h-word w (h = w*64 .. w*64+63 = n-tiles
// 4w..4w+3). W1 as bf16 B-fragments in REGISTERS (loaded once). Per t: x tile
// (16x120 fp32) -> bf16 [16][128] XOR-swizzled LDS (double-buffered, depth-1
// global prefetch), 16 x mfma_f32_16x16x32_bf16 per wave, LIF on C-frags,
// ballots repacked to per-batch h-word masks.
// A/B fragment k-order only needs A/B-consistency (dot product is k-order
// invariant); row/col = lane&15 matches the verified C layout (m89).
// ---------------------------------------------------------------------------
__global__ __launch_bounds__(256) void k_l1(
    const float* __restrict__ x, const float* __restrict__ W1,
    const float* __restrict__ b1, u64* __restrict__ s1m)
{
  __shared__ ushort A_sh[2][16 * 128];      // 8 KB, XOR-swizzled rows
  const int tid  = threadIdx.x;
  const int lane = tid & 63;
  const int w    = tid >> 6;                // wave id = h-word id
  const int b0   = blockIdx.x * 16;
  const int rr   = lane & 15;               // A-row / B-col / C-col
  const int hi   = lane >> 4;

  // ---- B fragments (W1 bf16) + bias, in registers, loaded once ----
  short8 bfrag[4][4];                       // [n-tile][k-step]
  float  bias[4];
#pragma unroll
  for (int nt = 0; nt < 4; ++nt) {
    const int n0 = w * 64 + nt * 16 + rr;
    bias[nt] = (n0 < HID) ? b1[n0] : 0.0f;
#pragma unroll
    for (int ks = 0; ks < 4; ++ks) {
      short8 bf = 0;
#pragma unroll
      for (int j = 0; j < 8; ++j) {
        const int k = ks * 32 + hi * 8 + j;
        float wv = (k < DIN && n0 < HID) ? W1[k * HID + n0] : 0.0f;
        bf[j] = (short)f2bf(wv);
      }
      bfrag[nt][ks] = bf;
    }
  }

  // ---- zero the k=120..127 pad of both buffers (never rewritten) ----
  if (tid < 32) {
    const int buf = tid >> 4, r = tid & 15;
    const int byt = r * 256 + (240 ^ ((r & 7) << 4));
    *(short8*)((char*)&A_sh[buf][0] + byt) = (short8)0;
  }

  // ---- x staging addresses: 240 threads load 8 fp32 each ----
  const bool ldr = (tid < 240);
  const int  seg = ldr ? tid / 5 : 0;       // 0..47
  const int  grp = ldr ? tid % 5 : 0;       // 0..4
  const int  br_ = seg / 3, cc = seg % 3;   // batch row 0..15, channel 0..2
  const float* src = x + ((size_t)(b0 + br_) * 3 + cc) * (S_STEPS * 40) + grp * 8;
  const int wbyte = br_ * 256 + ((((cc * 40 + grp * 8) * 2)) ^ ((br_ & 7) << 4));

  float4 p0 = {0,0,0,0}, p1 = {0,0,0,0};
  if (ldr) { p0 = *(const float4*)(src); p1 = *(const float4*)(src + 4); }
  if (ldr) {
    short8 a;
    a[0]=(short)f2bf(p0.x); a[1]=(short)f2bf(p0.y); a[2]=(short)f2bf(p0.z); a[3]=(short)f2bf(p0.w);
    a[4]=(short)f2bf(p1.x); a[5]=(short)f2bf(p1.y); a[6]=(short)f2bf(p1.z); a[7]=(short)f2bf(p1.w);
    *(short8*)((char*)&A_sh[0][0] + wbyte) = a;
  }

  float vst[4][4] = {{0,0,0,0},{0,0,0,0},{0,0,0,0},{0,0,0,0}};
  const int g  = lane >> 2;                 // pack: batch group
  const int r_ = lane & 3;                  // pack: C-reg select
  __syncthreads();

#pragma unroll 1
  for (int t = 0; t < S_STEPS; ++t) {
    const int buf = t & 1;
    // prefetch t+1 (issued first; consumed after barrier below)
    if (t + 1 < S_STEPS && ldr) {
      p0 = *(const float4*)(src + (t + 1) * 40);
      p1 = *(const float4*)(src + (t + 1) * 40 + 4);
    }
    // A fragments for this t
    short8 af[4];
#pragma unroll
    for (int ks = 0; ks < 4; ++ks) {
      const int byt = rr * 256 + ((ks * 64 + hi * 16) ^ ((rr & 7) << 4));
      af[ks] = *(const short8*)((const char*)&A_sh[buf][0] + byt);
    }
    // MFMA + LIF + ballot-pack
    u64 word = 0;
#pragma unroll
    for (int nt = 0; nt < 4; ++nt) {
      f32x4 acc = {0.f, 0.f, 0.f, 0.f};
#pragma unroll
      for (int ks = 0; ks < 4; ++ks)
        acc = __builtin_amdgcn_mfma_f32_16x16x32_bf16(af[ks], bfrag[nt][ks], acc, 0, 0, 0);
      u64 q0, q1, q2, q3;
      { float v = vst[nt][0]; v += 0.5f*((acc[0]+bias[nt]) - v); bool sp = v>=1.0f; vst[nt][0] = sp?0.f:v; q0 = __ballot(sp); }
      { float v = vst[nt][1]; v += 0.5f*((acc[1]+bias[nt]) - v); bool sp = v>=1.0f; vst[nt][1] = sp?0.f:v; q1 = __ballot(sp); }
      { float v = vst[nt][2]; v += 0.5f*((acc[2]+bias[nt]) - v); bool sp = v>=1.0f; vst[nt][2] = sp?0.f:v; q2 = __ballot(sp); }
      { float v = vst[nt][3]; v += 0.5f*((acc[3]+bias[nt]) - v); bool sp = v>=1.0f; vst[nt][3] = sp?0.f:v; q3 = __ballot(sp); }
      const u64 sel = (r_ == 0) ? q0 : ((r_ == 1) ? q1 : ((r_ == 2) ? q2 : q3));
      word |= ((sel >> (g * 16)) & 0xFFFFull) << (nt * 16);
    }
    if (lane < 16)
      s1m[((size_t)t * BATCH + b0 + lane) * 4 + w] = word;
    __syncthreads();
    if (t + 1 < S_STEPS && ldr) {
      short8 a;
      a[0]=(short)f2bf(p0.x); a[1]=(short)f2bf(p0.y); a[2]=(short)f2bf(p0.z); a[3]=(short)f2bf(p0.w);
      a[4]=(short)f2bf(p1.x); a[5]=(short)f2bf(p1.y); a[6]=(short)f2bf(p1.z); a[7]=(short)f2bf(p1.w);
      *(short8*)((char*)&A_sh[buf ^ 1][0] + wbyte) = a;
    }
    __syncthreads();
  }
}

// ---------------------------------------------------------------------------
// k_rec: recurrent layer from spike masks. W bf16 in LDS (80 KB -> 2 blk/CU).
// grid 512 x 256; block = 4 batches; next-t mask prefetch.
// ---------------------------------------------------------------------------
template <bool CNT>
__global__ __launch_bounds__(256) void k_rec(
    const float* __restrict__ W, const float* __restrict__ bias,
    const u64* __restrict__ min_, u64* __restrict__ mout,
    float* __restrict__ cnt)
{
  extern __shared__ ushort Ws[];            // 80,000 B
  const int tid  = threadIdx.x;
  const int b0   = blockIdx.x * 4;
  const int lane = tid & 63;
  const bool act = tid < HID;

  for (int idx = tid; idx < HID * HID; idx += 256) Ws[idx] = f2bf(W[idx]);
  const float bv = act ? bias[tid] : 0.0f;
  float v[4]  = {0, 0, 0, 0};
  float c4[4] = {0, 0, 0, 0};

  u64 nxt[4][4];
#pragma unroll
  for (int i = 0; i < 4; ++i)
#pragma unroll
    for (int w = 0; w < 4; ++w) nxt[i][w] = min_[((size_t)0 * BATCH + b0 + i) * 4 + w];
  __syncthreads();

#pragma unroll 1
  for (int t = 0; t < S_STEPS; ++t) {
    u64 mm[4][4];
#pragma unroll
    for (int i = 0; i < 4; ++i)
#pragma unroll
      for (int w = 0; w < 4; ++w) mm[i][w] = nxt[i][w];
    if (t + 1 < S_STEPS) {
      const u64* np = min_ + ((size_t)(t + 1) * BATCH + b0) * 4;
#pragma unroll
      for (int i = 0; i < 4; ++i)
#pragma unroll
        for (int w = 0; w < 4; ++w) nxt[i][w] = np[i * 4 + w];
    }

    float acc[4] = {bv, bv, bv, bv};
#pragma unroll
    for (int w = 0; w < 4; ++w) {
      while ((mm[0][w] | mm[1][w] | mm[2][w] | mm[3][w]) != 0ull) {
#pragma unroll
        for (int i = 0; i < 4; ++i) {
          u64 m = mm[i][w];
          if (m) {                          // wave-uniform branch
            int k = __builtin_ctzll(m);
            mm[i][w] = m & (m - 1);
            acc[i] += bf2f(Ws[(w * 64 + k) * HID + tid]);
          }
        }
      }
    }

#pragma unroll
    for (int i = 0; i < 4; ++i) {
      v[i] = v[i] + 0.5f * (acc[i] - v[i]);
      bool sp = act && (v[i] >= 1.0f);
      if (sp) v[i] = 0.0f;
      if (CNT) c4[i] += sp ? 1.0f : 0.0f;
      u64 bal = __ballot(sp);
      if (mout && lane == 0)
        mout[((size_t)t * BATCH + b0 + i) * 4 + (tid >> 6)] = bal;
    }
  }

  if (CNT && act) {
#pragma unroll
    for (int i = 0; i < 4; ++i)
      cnt[(size_t)(b0 + i) * HID + tid] = c4[i];
  }
}

// ---------------------------------------------------------------------------
// k_readout: out = (cnt/101) @ Wr + br, log_softmax over 12 classes.
// ---------------------------------------------------------------------------
__global__ __launch_bounds__(256) void k_readout(
    const float* __restrict__ cnt, const float* __restrict__ Wr,
    const float* __restrict__ br, float* __restrict__ out)
{
  __shared__ float cs[64 * HID];
  __shared__ float Wrs[HID * DOUT];
  __shared__ float brs[DOUT];
  __shared__ float os[64 * DOUT];
  const int tid = threadIdx.x;
  const int b0  = blockIdx.x * 64;

#pragma unroll
  for (int r = 0; r < 50; ++r)
    cs[r * 256 + tid] = cnt[(size_t)b0 * HID + r * 256 + tid];
  for (int idx = tid; idx < HID * DOUT; idx += 256) Wrs[idx] = Wr[idx];
  if (tid < DOUT) brs[tid] = br[tid];
  __syncthreads();

#pragma unroll
  for (int rep = 0; rep < 3; ++rep) {
    int idx = rep * 256 + tid;
    int bl = idx / DOUT, j = idx % DOUT;
    float a = 0.0f;
    for (int k = 0; k < HID; ++k)
      a += cs[bl * HID + k] * Wrs[k * DOUT + j];
    os[idx] = a * (1.0f / 101.0f) + brs[j];
  }
  __syncthreads();

  if (tid < 64) {
    float o[DOUT];
#pragma unroll
    for (int j = 0; j < DOUT; ++j) o[j] = os[tid * DOUT + j];
    float mx = o[0];
#pragma unroll
    for (int j = 1; j < DOUT; ++j) mx = fmaxf(mx, o[j]);
    float s = 0.0f;
#pragma unroll
    for (int j = 0; j < DOUT; ++j) s += expf(o[j] - mx);
    float ls = logf(s);
    float* op = out + (size_t)(b0 + tid) * DOUT;
#pragma unroll
    for (int j = 0; j < DOUT; ++j) op[j] = o[j] - mx - ls;
  }
}

// ---------------------------------------------------------------------------
extern "C" void kernel_launch(void* const* d_in, const int* in_sizes, int n_in,
                              void* d_out, int out_size, void* d_ws, size_t ws_size,
                              hipStream_t stream)
{
  const float* x  = (const float*)d_in[0];
  const float* W1 = (const float*)d_in[1];
  const float* b1 = (const float*)d_in[2];
  const float* W2 = (const float*)d_in[3];
  const float* b2 = (const float*)d_in[4];
  const float* W3 = (const float*)d_in[5];
  const float* b3 = (const float*)d_in[6];
  const float* Wr = (const float*)d_in[7];
  const float* br = (const float*)d_in[8];
  float* out = (float*)d_out;

  char* wsp = (char*)d_ws;
  const size_t mbytes = (size_t)S_STEPS * BATCH * 4 * sizeof(u64); // 6,619,136 B
  u64* s1m   = (u64*)(wsp);
  u64* s2m   = (u64*)(wsp + mbytes);
  float* cnt = (float*)(wsp + 2 * mbytes);   // total ~14.9 MB

  {
    void (*f2)(const float*, const float*, const u64*, u64*, float*) = k_rec<false>;
    void (*f3)(const float*, const float*, const u64*, u64*, float*) = k_rec<true>;
    hipFuncSetAttribute((const void*)f2, hipFuncAttributeMaxDynamicSharedMemorySize, 80000);
    hipFuncSetAttribute((const void*)f3, hipFuncAttributeMaxDynamicSharedMemorySize, 80000);
  }

  k_l1<<<BATCH / 16, 256, 0, stream>>>(x, W1, b1, s1m);
  k_rec<false><<<BATCH / 4, 256, 80000, stream>>>(W2, b2, s1m, s2m, nullptr);
  k_rec<true ><<<BATCH / 4, 256, 80000, stream>>>(W3, b3, s2m, nullptr, cnt);
  k_readout<<<32, 256, 0, stream>>>(cnt, Wr, br, out);
}